// Round 14
// baseline (775.039 us; speedup 1.0000x reference)
//
#include <hip/hip_runtime.h>

#define NN 64
#define NI 6
#define TT 1024
#define BB 1024
#define TB (TT * BB)
#define NSCALE 0.13416407864998738f        // sqrt(2/alpha) * sigma
#define ARNSCALE 0.013416407864998739f     // alpha * NSCALE
#define RREC 72                            // rnu record: 64 rn' (-> x) + 6 uterm + 2 pad(0)
#define BSTRIDE (TT * RREC)                // 73728 floats per batch

__device__ __forceinline__ float rdlane(float v, int l) {
    return __int_as_float(__builtin_amdgcn_readlane(__float_as_int(v), l));
}

// ---------------- Pass 1: build rnu[b][t][72] in d_ws ----------------
// record[0..63]  = ARNSCALE * rn[n][t][b]   (transposed, n contiguous)
// record[64..69] = u[i][t][b] + NSCALE*inn[i][t][b];  [70..71] = 0
__global__ __launch_bounds__(256) void build_rnu(
    const float* __restrict__ u,
    const float* __restrict__ rn,
    const float* __restrict__ inn,
    float* __restrict__ rnu)
{
    const int blk = blockIdx.x;
    const int t   = blk >> 4;
    const int b0  = (blk & 15) * 64;
    const int tid = threadIdx.x;

    __shared__ float lds[64][65];

    {   // read rn 64n x 64b tile (coalesced along b), store transposed + prescale
        const int c  = tid & 63;
        const int r0 = tid >> 6;
#pragma unroll
        for (int it = 0; it < 16; ++it) {
            const int n = 4 * it + r0;
            lds[c][n] = ARNSCALE * rn[n * TB + t * BB + b0 + c];
        }
    }
    __syncthreads();
    {   // write 64 b-rows, 64 n contiguous each (coalesced)
        const int cn = tid & 63;
        const int r0 = tid >> 6;
#pragma unroll
        for (int it = 0; it < 16; ++it) {
            const int r = 4 * it + r0;
            rnu[(b0 + r) * BSTRIDE + t * RREC + cn] = lds[r][cn];
        }
    }
    {   // uterm (+ zero pad) — 8 floats per b
        const int i  = tid & 7;
        const int br = tid >> 3;
#pragma unroll
        for (int it = 0; it < 2; ++it) {
            const int b = br + 32 * it;
            float v = 0.0f;
            if (i < NI) {
                const int g = i * TB + t * BB + b0 + b;
                v = fmaf(NSCALE, inn[g], u[g]);
            }
            rnu[(b0 + b) * BSTRIDE + t * RREC + 64 + i] = v;
        }
    }
}

// ---------------- Pass 2: recurrence, 2 batches/wave LDS-broadcast ----------------
// 512 blocks x 64 thr (2 waves/CU). Lane l: half h=l>>5 = batch, p=l&31, owns
// neurons 2p,2p+1. One 18x ds_read_b128 sweep per step feeds BOTH batches (the
// halves read different rows, bank-offset by 16 -> conflict-free). LDS-pipe cost
// per CU per step halves vs 1-batch/wave: 36 b128 instead of 72. Weights (2x72)
// asm-pinned into VGPRs. Wave-synchronous: no barriers.
__global__ __launch_bounds__(64, 1) void latent_rnn_2b(
    const float* __restrict__ rn_in,  // (B, T, 72) — reads
    float* __restrict__ x_out,        // (B, T, 72) — x writeback (same buffer)
    const float* __restrict__ Winp,   // (64, 6)
    const float* __restrict__ Wrec)   // (64, 64)
{
    const int hw = blockIdx.x;                   // 512 blocks
    const int g  = (hw & 7) * 64 + (hw >> 3);    // XCD swizzle: 128 batches/XCD
    const int b0 = g * 2;
    const int l  = threadIdx.x;
    const int h  = l >> 5;                       // batch half
    const int p  = l & 31;                       // neuron pair index
    const int n0 = 2 * p;                        // neurons n0, n0+1
    const int bb = b0 + h;

    // [batch-in-block][parity][88]: halves' rows bank-offset by 16 -> disjoint
    __shared__ __align__(16) float xs[2][2][88];

    // ---- per-lane weights for 2 neurons: [0..63]=Wrec row, [64..69]=Winp, pads 0
    float w0[72], w1[72];
#pragma unroll
    for (int k = 0; k < NN; k += 4) {
        const float4 a = *reinterpret_cast<const float4*>(Wrec + n0 * NN + k);
        const float4 b = *reinterpret_cast<const float4*>(Wrec + (n0 + 1) * NN + k);
        w0[k] = a.x; w0[k+1] = a.y; w0[k+2] = a.z; w0[k+3] = a.w;
        w1[k] = b.x; w1[k+1] = b.y; w1[k+2] = b.z; w1[k+3] = b.w;
    }
#pragma unroll
    for (int i = 0; i < NI; ++i) {
        w0[64 + i] = Winp[n0 * NI + i];
        w1[64 + i] = Winp[(n0 + 1) * NI + i];
    }
    w0[70] = 0.f; w0[71] = 0.f; w1[70] = 0.f; w1[71] = 0.f;
    // pin: values become opaque -> cannot be re-derived from memory in the loop
#pragma unroll
    for (int k = 0; k < 72; ++k) asm volatile("" : "+v"(w0[k]));
#pragma unroll
    for (int k = 0; k < 72; ++k) asm volatile("" : "+v"(w1[k]));

    const float* rptr = rn_in + bb * BSTRIDE + n0;            // rn' pair view (b64)
    const float* uptr = rn_in + bb * BSTRIDE + 64 + (p & 7);  // uterm view (p<8 live)
    float*       xdst = x_out + bb * BSTRIDE + n0;            // x pair writeback

    // ---- init parity 0: x[0] = 0; uterm(0) incl. zero pads (record pads are 0) ----
    *reinterpret_cast<float2*>(&xs[h][0][n0]) = make_float2(0.f, 0.f);
    if (p < 8) xs[h][0][64 + p] = uptr[0];

    // prefetch rings (depth 4): rnb = rn'(t) pair, utb = uterm(t+1)
    float2 rnb[4];
    float  utb[4];
#pragma unroll
    for (int d = 0; d < 4; ++d) {
        rnb[d] = *reinterpret_cast<const float2*>(rptr + d * RREC);
        utb[d] = uptr[(d + 1) * RREC];
    }

    float x0 = 0.0f, x1 = 0.0f;

#define STEP(tcur, slot, P)                                                   \
    do {                                                                      \
        const float2 rcur = rnb[slot];                                        \
        const float  ucur = utb[slot];                                        \
        { const int tp = ((tcur) + 4 < TT - 2) ? (tcur) + 4 : TT - 2;         \
          rnb[slot] = *reinterpret_cast<const float2*>(rptr + tp * RREC); }   \
        { const int tq = ((tcur) + 5 < TT - 2) ? (tcur) + 5 : TT - 2;         \
          utb[slot] = uptr[tq * RREC]; }                                      \
        const float4* row = reinterpret_cast<const float4*>(&xs[h][P][0]);    \
        float a0 = 0.f, a1 = 0.f, a2 = 0.f, a3 = 0.f;                         \
        float c0 = 0.f, c1 = 0.f, c2 = 0.f, c3 = 0.f;                         \
        _Pragma("unroll")                                                     \
        for (int q = 0; q < 18; ++q) {                                        \
            const float4 v = row[q];                                          \
            a0 = fmaf(v.x, w0[4*q+0], a0); c0 = fmaf(v.x, w1[4*q+0], c0);     \
            a1 = fmaf(v.y, w0[4*q+1], a1); c1 = fmaf(v.y, w1[4*q+1], c1);     \
            a2 = fmaf(v.z, w0[4*q+2], a2); c2 = fmaf(v.z, w1[4*q+2], c2);     \
            a3 = fmaf(v.w, w0[4*q+3], a3); c3 = fmaf(v.w, w1[4*q+3], c3);     \
        }                                                                     \
        const float pre0 = (a0 + a1) + (a2 + a3);                             \
        const float pre1 = (c0 + c1) + (c2 + c3);                             \
        const float xn0 = fmaf(0.9f, x0, fmaf(0.1f, fmaxf(pre0, 0.f), rcur.x)); \
        const float xn1 = fmaf(0.9f, x1, fmaf(0.1f, fmaxf(pre1, 0.f), rcur.y)); \
        x0 = xn0; x1 = xn1;                                                   \
        *reinterpret_cast<float2*>(&xs[h][(P) ^ 1][n0]) = make_float2(xn0, xn1); \
        if (p < 8) xs[h][(P) ^ 1][64 + p] = ucur;                             \
        *reinterpret_cast<float2*>(xdst + (tcur) * RREC) = make_float2(xn0, xn1); \
    } while (0)

#pragma unroll 1
    for (int t = 0; t < 1020; t += 4) {
        STEP(t + 0, 0, 0);
        STEP(t + 1, 1, 1);
        STEP(t + 2, 2, 0);
        STEP(t + 3, 3, 1);
    }
    STEP(1020, 0, 0);
    STEP(1021, 1, 1);
    STEP(1022, 2, 0);
#undef STEP
}

// ---------------- Pass 3: transpose + fused output projection ----------------
// states[n][t][b] = (t==0) ? 0 : rnu[b][t-1][n];  outputs = states @ Wout^T.
__global__ __launch_bounds__(256) void trans_out(
    const float* __restrict__ rnu,
    const float* __restrict__ Wout,     // (2, 64)
    float* __restrict__ states,         // (64, T, B)
    float* __restrict__ outputs)        // (2, T, B)
{
    const int blk = blockIdx.x;
    const int t   = blk >> 4;
    const int b0  = (blk & 15) * 64;
    const int tid = threadIdx.x;

    __shared__ float xt[64][65];   // [b][n]
    __shared__ float wo[2][64];

    if (tid < 128) wo[tid >> 6][tid & 63] = Wout[tid];

    const int col = tid & 63;
    const int r0  = tid >> 6;
    if (t == 0) {
#pragma unroll
        for (int it = 0; it < 16; ++it) xt[4 * it + r0][col] = 0.0f;
    } else {
#pragma unroll
        for (int it = 0; it < 16; ++it) {
            const int r = 4 * it + r0;   // batch within tile
            xt[r][col] = rnu[(b0 + r) * BSTRIDE + (t - 1) * RREC + col];
        }
    }
    __syncthreads();

#pragma unroll
    for (int it = 0; it < 16; ++it) {
        const int n = 4 * it + r0;
        states[n * TB + t * BB + b0 + col] = xt[col][n];
    }

    if (tid < 128) {
        const int o  = tid >> 6;
        const int bb = tid & 63;
        float acc = 0.0f;
#pragma unroll
        for (int k = 0; k < NN; ++k) acc = fmaf(xt[bb][k], wo[o][k], acc);
        outputs[o * TB + t * BB + b0 + bb] = acc;
    }
}

// ---------------- Fallback (no-workspace path, proven correct) ----------------
#define BARRIER() do {                                                        \
    __builtin_amdgcn_sched_barrier(0);                                        \
    asm volatile("s_waitcnt lgkmcnt(0)\n\ts_barrier" ::: "memory");           \
    __builtin_amdgcn_sched_barrier(0);                                        \
} while (0)

__global__ __launch_bounds__(256, 1) void latent_rnn_fb(
    const float* __restrict__ u, const float* __restrict__ rn,
    const float* __restrict__ inn, const float* __restrict__ Winp,
    const float* __restrict__ Wrec, float* __restrict__ states)
{
    const int hw  = blockIdx.x;
    const int lb  = (hw & 7) * 32 + (hw >> 3);
    const int b0  = lb * 4;
    const int tid = threadIdx.x;
    const int l   = tid & 63;
    const int w   = tid >> 6;
    const int n   = tid >> 2;
    const int bs  = tid & 3;

    __shared__ float rnT[2][NN][5];
    __shared__ float xT[2][NN][5];
    __shared__ float iT[2][4][8];

    float wreg[NN];
#pragma unroll
    for (int k = 0; k < NN; k += 4) {
        const float4 w4 = *reinterpret_cast<const float4*>(Wrec + l * NN + k);
        wreg[k] = w4.x; wreg[k+1] = w4.y; wreg[k+2] = w4.z; wreg[k+3] = w4.w;
    }
    float wi[NI];
#pragma unroll
    for (int i = 0; i < NI; ++i) wi[i] = Winp[l * NI + i];

    const float* rsrc = rn + n * TB + b0 + bs;
    float*       sdst = states + n * TB + b0 + bs;
    const bool  ist  = (tid < NI * 4);
    const int   ii   = tid >> 2;
    const int   ib   = tid & 3;
    const float* usrc = u   + ii * TB + b0 + ib;
    const float* isrc = inn + ii * TB + b0 + ib;

    rnT[0][n][bs] = rsrc[0];
    if (ist) iT[0][ib][ii] = fmaf(NSCALE, isrc[0], usrc[0]);
    xT[0][l][w] = 0.0f;

    float rnPF[4], uPF[4], iPF[4];
#pragma unroll
    for (int d = 0; d < 4; ++d) {
        rnPF[d] = rsrc[(d + 1) * BB];
        if (ist) { uPF[d] = usrc[(d + 1) * BB]; iPF[d] = isrc[(d + 1) * BB]; }
    }
    __syncthreads();

    float xreg = 0.0f;

#define FSTEP(tcur, slot, CC)                                                 \
  {                                                                           \
    sdst[(tcur) * BB] = xT[CC][n][bs];                                        \
    const float rcur = rnT[CC][l][w];                                         \
    const float4 iv0 = *reinterpret_cast<const float4*>(&iT[CC][w][0]);       \
    const float2 iv1 = *reinterpret_cast<const float2*>(&iT[CC][w][4]);       \
    float a0 = 0.f, a1 = 0.f, a2 = 0.f, a3 = 0.f;                             \
    _Pragma("unroll")                                                         \
    for (int k = 0; k < NN; k += 4) {                                         \
        a0 = fmaf(rdlane(xreg, k + 0), wreg[k + 0], a0);                      \
        a1 = fmaf(rdlane(xreg, k + 1), wreg[k + 1], a1);                      \
        a2 = fmaf(rdlane(xreg, k + 2), wreg[k + 2], a2);                      \
        a3 = fmaf(rdlane(xreg, k + 3), wreg[k + 3], a3);                      \
    }                                                                         \
    a0 = fmaf(iv0.x, wi[0], a0); a1 = fmaf(iv0.y, wi[1], a1);                 \
    a2 = fmaf(iv0.z, wi[2], a2); a3 = fmaf(iv0.w, wi[3], a3);                 \
    a0 = fmaf(iv1.x, wi[4], a0); a1 = fmaf(iv1.y, wi[5], a1);                 \
    const float pre = (a0 + a1) + (a2 + a3);                                  \
    const float xn  = fmaf(0.9f, xreg,                                        \
                           fmaf(0.1f, fmaxf(pre, 0.f), ARNSCALE * rcur));     \
    xreg = xn;                                                                \
    xT[(CC) ^ 1][l][w] = xn;                                                  \
    rnT[(CC) ^ 1][n][bs] = rnPF[slot];                                        \
    if (ist) iT[(CC) ^ 1][ib][ii] = fmaf(NSCALE, iPF[slot], uPF[slot]);       \
    { int tp = (tcur) + 5; if (tp > TT - 2) tp = TT - 2;                      \
      rnPF[slot] = rsrc[tp * BB];                                             \
      if (ist) { uPF[slot] = usrc[tp * BB]; iPF[slot] = isrc[tp * BB]; } }    \
    BARRIER();                                                                \
  }

#pragma unroll 1
    for (int t = 0; t < 1020; t += 4) {
        FSTEP(t + 0, 0, 0);
        FSTEP(t + 1, 1, 1);
        FSTEP(t + 2, 2, 0);
        FSTEP(t + 3, 3, 1);
    }
    FSTEP(1020, 0, 0);
    FSTEP(1021, 1, 1);
    FSTEP(1022, 2, 0);
#undef FSTEP

    sdst[(TT - 1) * BB] = xT[1][n][bs];
}

__global__ __launch_bounds__(256) void out_proj(
    const float* __restrict__ states,
    const float* __restrict__ Wout,
    float* __restrict__ outputs)
{
    const int g4 = (blockIdx.x * 256 + threadIdx.x) * 4;
    float4 a0 = {0.f, 0.f, 0.f, 0.f};
    float4 a1 = {0.f, 0.f, 0.f, 0.f};
#pragma unroll
    for (int k = 0; k < NN; ++k) {
        const float4 s = *reinterpret_cast<const float4*>(states + k * TB + g4);
        const float w0 = Wout[k];
        const float w1 = Wout[NN + k];
        a0.x = fmaf(s.x, w0, a0.x); a0.y = fmaf(s.y, w0, a0.y);
        a0.z = fmaf(s.z, w0, a0.z); a0.w = fmaf(s.w, w0, a0.w);
        a1.x = fmaf(s.x, w1, a1.x); a1.y = fmaf(s.y, w1, a1.y);
        a1.z = fmaf(s.z, w1, a1.z); a1.w = fmaf(s.w, w1, a1.w);
    }
    *reinterpret_cast<float4*>(outputs + g4)      = a0;
    *reinterpret_cast<float4*>(outputs + TB + g4) = a1;
}

extern "C" void kernel_launch(void* const* d_in, const int* in_sizes, int n_in,
                              void* d_out, int out_size, void* d_ws, size_t ws_size,
                              hipStream_t stream) {
    const float* u    = (const float*)d_in[0];
    const float* rn   = (const float*)d_in[1];
    const float* inn  = (const float*)d_in[2];
    const float* Winp = (const float*)d_in[3];
    const float* Wrec = (const float*)d_in[4];
    const float* Wout = (const float*)d_in[5];

    float* states  = (float*)d_out;                          // 64*1024*1024
    float* outputs = (float*)d_out + (size_t)NN * TT * BB;   // 2*1024*1024

    const size_t need = (size_t)BB * TT * RREC * sizeof(float);  // ~302 MB
    if (ws_size >= need) {
        float* rnu = (float*)d_ws;
        build_rnu<<<TT * 16, 256, 0, stream>>>(u, rn, inn, rnu);
        latent_rnn_2b<<<512, 64, 0, stream>>>(rnu, rnu, Winp, Wrec);
        trans_out<<<TT * 16, 256, 0, stream>>>(rnu, Wout, states, outputs);
    } else {
        latent_rnn_fb<<<256, 256, 0, stream>>>(u, rn, inn, Winp, Wrec, states);
        out_proj<<<1024, 256, 0, stream>>>(states, Wout, outputs);
    }
}

// Round 15
// 693.727 us; speedup vs baseline: 1.1172x; 1.1172x over previous
//
#include <hip/hip_runtime.h>

#define NN 64
#define NI 6
#define TT 1024
#define BB 1024
#define TB (TT * BB)
#define NSCALE 0.13416407864998738f        // sqrt(2/alpha) * sigma
#define ARNSCALE 0.013416407864998739f     // alpha * NSCALE
#define RREC 72                            // rnu record: 64 rn' (-> x) + 6 uterm + 2 pad(0)
#define BSTRIDE (TT * RREC)                // 73728 floats per batch

__device__ __forceinline__ float rdlane(float v, int l) {
    return __int_as_float(__builtin_amdgcn_readlane(__float_as_int(v), l));
}

// ---------------- Pass 1: build rnu[b][t][72] in d_ws ----------------
// record[0..63]  = ARNSCALE * rn[n][t][b]   (transposed, n contiguous)
// record[64..69] = u[i][t][b] + NSCALE*inn[i][t][b];  [70..71] = 0
__global__ __launch_bounds__(256) void build_rnu(
    const float* __restrict__ u,
    const float* __restrict__ rn,
    const float* __restrict__ inn,
    float* __restrict__ rnu)
{
    const int blk = blockIdx.x;
    const int t   = blk >> 4;
    const int b0  = (blk & 15) * 64;
    const int tid = threadIdx.x;

    __shared__ float lds[64][65];

    {   // read rn 64n x 64b tile (coalesced along b), store transposed + prescale
        const int c  = tid & 63;
        const int r0 = tid >> 6;
#pragma unroll
        for (int it = 0; it < 16; ++it) {
            const int n = 4 * it + r0;
            lds[c][n] = ARNSCALE * rn[n * TB + t * BB + b0 + c];
        }
    }
    __syncthreads();
    {   // write 64 b-rows, 64 n contiguous each (coalesced)
        const int cn = tid & 63;
        const int r0 = tid >> 6;
#pragma unroll
        for (int it = 0; it < 16; ++it) {
            const int r = 4 * it + r0;
            rnu[(b0 + r) * BSTRIDE + t * RREC + cn] = lds[r][cn];
        }
    }
    {   // uterm (+ zero pad) — 8 floats per b
        const int i  = tid & 7;
        const int br = tid >> 3;
#pragma unroll
        for (int it = 0; it < 2; ++it) {
            const int b = br + 32 * it;
            float v = 0.0f;
            if (i < NI) {
                const int g = i * TB + t * BB + b0 + b;
                v = fmaf(NSCALE, inn[g], u[g]);
            }
            rnu[(b0 + b) * BSTRIDE + t * RREC + 64 + i] = v;
        }
    }
}

// ---------------- Pass 2: recurrence, LDS-broadcast x, PINNED weights ----------------
// 1024 blocks x 64 thr (4 waves/CU). lane = neuron, block = batch. x-broadcast via
// 18 same-addr ds_read_b128 (conflict-free broadcast). Weights (72 VGPRs) asm-pinned:
// round-13's VGPR_Count=60 proved the compiler re-loaded W from global EVERY STEP
// (~450 cyc/step vmcnt stall); round-14 proved the pin holds at block=64.
__global__ __launch_bounds__(64, 1) void latent_rnn_ldsp(
    const float* __restrict__ rn_in,  // (B, T, 72) — reads
    float* __restrict__ x_out,        // (B, T, 72) — x writeback (same buffer)
    const float* __restrict__ Winp,   // (64, 6)
    const float* __restrict__ Wrec)   // (64, 64)
{
    const int hw = blockIdx.x;
    const int b  = (hw & 7) * 128 + (hw >> 3);   // XCD swizzle: 128 batches/XCD
    const int n  = threadIdx.x;

    __shared__ __align__(16) float xs[2][80];    // [parity][x(64) | uterm(8) | pad]

    // ---- per-lane weights: w[0..63] = Wrec row, w[64..69] = Winp row, w[70..71]=0
    float w[72];
#pragma unroll
    for (int k = 0; k < NN; k += 4) {
        const float4 w4 = *reinterpret_cast<const float4*>(Wrec + n * NN + k);
        w[k] = w4.x; w[k + 1] = w4.y; w[k + 2] = w4.z; w[k + 3] = w4.w;
    }
#pragma unroll
    for (int i = 0; i < NI; ++i) w[64 + i] = Winp[n * NI + i];
    w[70] = 0.0f; w[71] = 0.0f;
    // PIN: opaque values -> cannot be re-derived from memory inside the loop
#pragma unroll
    for (int k = 0; k < 72; ++k) asm volatile("" : "+v"(w[k]));

    const float* rptr = rn_in + b * BSTRIDE + n;             // rn' lane view
    const float* uptr = rn_in + b * BSTRIDE + 64 + (n & 7);  // uterm lane view
    float*       xdst = x_out + b * BSTRIDE + n;             // x writeback view

    // ---- init parity 0: x[0] = 0, uterm(0) ----
    xs[0][n] = 0.0f;
    if (n < 8) xs[0][64 + n] = uptr[0];

    // prefetch rings (depth 4, static slots): rnb holds rn'(t), utb holds uterm(t+1)
    float rnb[4], utb[4];
#pragma unroll
    for (int d = 0; d < 4; ++d) {
        rnb[d] = rptr[d * RREC];
        utb[d] = uptr[(d + 1) * RREC];
    }

    float xreg = 0.0f;

#define STEP(tcur, slot, P)                                                   \
    do {                                                                      \
        const float rcur = rnb[slot];                                         \
        const float ucur = utb[slot];   /* uterm(t+1) */                      \
        { const int tp = ((tcur) + 4 < TT - 2) ? (tcur) + 4 : TT - 2;         \
          rnb[slot] = rptr[tp * RREC]; }                                      \
        { const int tq = ((tcur) + 5 < TT - 2) ? (tcur) + 5 : TT - 2;         \
          utb[slot] = uptr[tq * RREC]; }                                      \
        /* broadcast-read the 72-float row: x[t] (0..63) + uterm[t] (64..71) */\
        const float4* row = reinterpret_cast<const float4*>(&xs[P][0]);       \
        float a0 = 0.f, a1 = 0.f, a2 = 0.f, a3 = 0.f;                         \
        _Pragma("unroll")                                                     \
        for (int q = 0; q < 18; ++q) {                                        \
            const float4 v = row[q];                                          \
            a0 = fmaf(v.x, w[4 * q + 0], a0);                                 \
            a1 = fmaf(v.y, w[4 * q + 1], a1);                                 \
            a2 = fmaf(v.z, w[4 * q + 2], a2);                                 \
            a3 = fmaf(v.w, w[4 * q + 3], a3);                                 \
        }                                                                     \
        const float pre = (a0 + a1) + (a2 + a3);                              \
        const float xn  = fmaf(0.9f, xreg,                                    \
                               fmaf(0.1f, fmaxf(pre, 0.f), rcur));            \
        xreg = xn;                                                            \
        xs[(P) ^ 1][n] = xn;                  /* x[t+1] for next step */      \
        if (n < 8) xs[(P) ^ 1][64 + n] = ucur;/* uterm[t+1] */                \
        xdst[(tcur) * RREC] = xn;             /* record[t] <- x[t+1] */       \
    } while (0)

#pragma unroll 1
    for (int t = 0; t < 1020; t += 4) {
        STEP(t + 0, 0, 0);
        STEP(t + 1, 1, 1);
        STEP(t + 2, 2, 0);
        STEP(t + 3, 3, 1);
    }
    STEP(1020, 0, 0);
    STEP(1021, 1, 1);
    STEP(1022, 2, 0);
#undef STEP
}

// ---------------- Pass 3: transpose + fused output projection ----------------
// states[n][t][b] = (t==0) ? 0 : rnu[b][t-1][n];  outputs = states @ Wout^T.
__global__ __launch_bounds__(256) void trans_out(
    const float* __restrict__ rnu,
    const float* __restrict__ Wout,     // (2, 64)
    float* __restrict__ states,         // (64, T, B)
    float* __restrict__ outputs)        // (2, T, B)
{
    const int blk = blockIdx.x;
    const int t   = blk >> 4;
    const int b0  = (blk & 15) * 64;
    const int tid = threadIdx.x;

    __shared__ float xt[64][65];   // [b][n]
    __shared__ float wo[2][64];

    if (tid < 128) wo[tid >> 6][tid & 63] = Wout[tid];

    const int col = tid & 63;
    const int r0  = tid >> 6;
    if (t == 0) {
#pragma unroll
        for (int it = 0; it < 16; ++it) xt[4 * it + r0][col] = 0.0f;
    } else {
#pragma unroll
        for (int it = 0; it < 16; ++it) {
            const int r = 4 * it + r0;   // batch within tile
            xt[r][col] = rnu[(b0 + r) * BSTRIDE + (t - 1) * RREC + col];
        }
    }
    __syncthreads();

#pragma unroll
    for (int it = 0; it < 16; ++it) {
        const int n = 4 * it + r0;
        states[n * TB + t * BB + b0 + col] = xt[col][n];
    }

    if (tid < 128) {
        const int o  = tid >> 6;
        const int bb = tid & 63;
        float acc = 0.0f;
#pragma unroll
        for (int k = 0; k < NN; ++k) acc = fmaf(xt[bb][k], wo[o][k], acc);
        outputs[o * TB + t * BB + b0 + bb] = acc;
    }
}

// ---------------- Fallback (no-workspace path, proven correct) ----------------
#define BARRIER() do {                                                        \
    __builtin_amdgcn_sched_barrier(0);                                        \
    asm volatile("s_waitcnt lgkmcnt(0)\n\ts_barrier" ::: "memory");           \
    __builtin_amdgcn_sched_barrier(0);                                        \
} while (0)

__global__ __launch_bounds__(256, 1) void latent_rnn_fb(
    const float* __restrict__ u, const float* __restrict__ rn,
    const float* __restrict__ inn, const float* __restrict__ Winp,
    const float* __restrict__ Wrec, float* __restrict__ states)
{
    const int hw  = blockIdx.x;
    const int lb  = (hw & 7) * 32 + (hw >> 3);
    const int b0  = lb * 4;
    const int tid = threadIdx.x;
    const int l   = tid & 63;
    const int w   = tid >> 6;
    const int n   = tid >> 2;
    const int bs  = tid & 3;

    __shared__ float rnT[2][NN][5];
    __shared__ float xT[2][NN][5];
    __shared__ float iT[2][4][8];

    float wreg[NN];
#pragma unroll
    for (int k = 0; k < NN; k += 4) {
        const float4 w4 = *reinterpret_cast<const float4*>(Wrec + l * NN + k);
        wreg[k] = w4.x; wreg[k+1] = w4.y; wreg[k+2] = w4.z; wreg[k+3] = w4.w;
    }
    float wi[NI];
#pragma unroll
    for (int i = 0; i < NI; ++i) wi[i] = Winp[l * NI + i];

    const float* rsrc = rn + n * TB + b0 + bs;
    float*       sdst = states + n * TB + b0 + bs;
    const bool  ist  = (tid < NI * 4);
    const int   ii   = tid >> 2;
    const int   ib   = tid & 3;
    const float* usrc = u   + ii * TB + b0 + ib;
    const float* isrc = inn + ii * TB + b0 + ib;

    rnT[0][n][bs] = rsrc[0];
    if (ist) iT[0][ib][ii] = fmaf(NSCALE, isrc[0], usrc[0]);
    xT[0][l][w] = 0.0f;

    float rnPF[4], uPF[4], iPF[4];
#pragma unroll
    for (int d = 0; d < 4; ++d) {
        rnPF[d] = rsrc[(d + 1) * BB];
        if (ist) { uPF[d] = usrc[(d + 1) * BB]; iPF[d] = isrc[(d + 1) * BB]; }
    }
    __syncthreads();

    float xreg = 0.0f;

#define FSTEP(tcur, slot, CC)                                                 \
  {                                                                           \
    sdst[(tcur) * BB] = xT[CC][n][bs];                                        \
    const float rcur = rnT[CC][l][w];                                         \
    const float4 iv0 = *reinterpret_cast<const float4*>(&iT[CC][w][0]);       \
    const float2 iv1 = *reinterpret_cast<const float2*>(&iT[CC][w][4]);       \
    float a0 = 0.f, a1 = 0.f, a2 = 0.f, a3 = 0.f;                             \
    _Pragma("unroll")                                                         \
    for (int k = 0; k < NN; k += 4) {                                         \
        a0 = fmaf(rdlane(xreg, k + 0), wreg[k + 0], a0);                      \
        a1 = fmaf(rdlane(xreg, k + 1), wreg[k + 1], a1);                      \
        a2 = fmaf(rdlane(xreg, k + 2), wreg[k + 2], a2);                      \
        a3 = fmaf(rdlane(xreg, k + 3), wreg[k + 3], a3);                      \
    }                                                                         \
    a0 = fmaf(iv0.x, wi[0], a0); a1 = fmaf(iv0.y, wi[1], a1);                 \
    a2 = fmaf(iv0.z, wi[2], a2); a3 = fmaf(iv0.w, wi[3], a3);                 \
    a0 = fmaf(iv1.x, wi[4], a0); a1 = fmaf(iv1.y, wi[5], a1);                 \
    const float pre = (a0 + a1) + (a2 + a3);                                  \
    const float xn  = fmaf(0.9f, xreg,                                        \
                           fmaf(0.1f, fmaxf(pre, 0.f), ARNSCALE * rcur));     \
    xreg = xn;                                                                \
    xT[(CC) ^ 1][l][w] = xn;                                                  \
    rnT[(CC) ^ 1][n][bs] = rnPF[slot];                                        \
    if (ist) iT[(CC) ^ 1][ib][ii] = fmaf(NSCALE, iPF[slot], uPF[slot]);       \
    { int tp = (tcur) + 5; if (tp > TT - 2) tp = TT - 2;                      \
      rnPF[slot] = rsrc[tp * BB];                                             \
      if (ist) { uPF[slot] = usrc[tp * BB]; iPF[slot] = isrc[tp * BB]; } }    \
    BARRIER();                                                                \
  }

#pragma unroll 1
    for (int t = 0; t < 1020; t += 4) {
        FSTEP(t + 0, 0, 0);
        FSTEP(t + 1, 1, 1);
        FSTEP(t + 2, 2, 0);
        FSTEP(t + 3, 3, 1);
    }
    FSTEP(1020, 0, 0);
    FSTEP(1021, 1, 1);
    FSTEP(1022, 2, 0);
#undef FSTEP

    sdst[(TT - 1) * BB] = xT[1][n][bs];
}

__global__ __launch_bounds__(256) void out_proj(
    const float* __restrict__ states,
    const float* __restrict__ Wout,
    float* __restrict__ outputs)
{
    const int g4 = (blockIdx.x * 256 + threadIdx.x) * 4;
    float4 a0 = {0.f, 0.f, 0.f, 0.f};
    float4 a1 = {0.f, 0.f, 0.f, 0.f};
#pragma unroll
    for (int k = 0; k < NN; ++k) {
        const float4 s = *reinterpret_cast<const float4*>(states + k * TB + g4);
        const float w0 = Wout[k];
        const float w1 = Wout[NN + k];
        a0.x = fmaf(s.x, w0, a0.x); a0.y = fmaf(s.y, w0, a0.y);
        a0.z = fmaf(s.z, w0, a0.z); a0.w = fmaf(s.w, w0, a0.w);
        a1.x = fmaf(s.x, w1, a1.x); a1.y = fmaf(s.y, w1, a1.y);
        a1.z = fmaf(s.z, w1, a1.z); a1.w = fmaf(s.w, w1, a1.w);
    }
    *reinterpret_cast<float4*>(outputs + g4)      = a0;
    *reinterpret_cast<float4*>(outputs + TB + g4) = a1;
}

extern "C" void kernel_launch(void* const* d_in, const int* in_sizes, int n_in,
                              void* d_out, int out_size, void* d_ws, size_t ws_size,
                              hipStream_t stream) {
    const float* u    = (const float*)d_in[0];
    const float* rn   = (const float*)d_in[1];
    const float* inn  = (const float*)d_in[2];
    const float* Winp = (const float*)d_in[3];
    const float* Wrec = (const float*)d_in[4];
    const float* Wout = (const float*)d_in[5];

    float* states  = (float*)d_out;                          // 64*1024*1024
    float* outputs = (float*)d_out + (size_t)NN * TT * BB;   // 2*1024*1024

    const size_t need = (size_t)BB * TT * RREC * sizeof(float);  // ~302 MB
    if (ws_size >= need) {
        float* rnu = (float*)d_ws;
        build_rnu<<<TT * 16, 256, 0, stream>>>(u, rn, inn, rnu);
        latent_rnn_ldsp<<<1024, 64, 0, stream>>>(rnu, rnu, Winp, Wrec);
        trans_out<<<TT * 16, 256, 0, stream>>>(rnu, Wout, states, outputs);
    } else {
        latent_rnn_fb<<<256, 256, 0, stream>>>(u, rn, inn, Winp, Wrec, states);
        out_proj<<<1024, 256, 0, stream>>>(states, Wout, outputs);
    }
}